// Round 1
// baseline (871.187 us; speedup 1.0000x reference)
//
#include <hip/hip_runtime.h>
#include <math.h>

#define BB 256
#define NN 512
#define DD 6
#define F_IN 62
#define HH 128
#define ND 7
#define TOTAL (BB*NN)   // 131072
#define TILE 64

// ---------------- counting sort of nodes by degree ----------------

__global__ void k_zero(unsigned int* ghist) {
    if (threadIdx.x < ND) ghist[threadIdx.x] = 0u;
}

__global__ __launch_bounds__(256) void k_hist(const int* __restrict__ e,
                                              int* __restrict__ deg,
                                              unsigned int* __restrict__ ghist) {
    __shared__ unsigned int lh[ND];
    int t = threadIdx.x;
    if (t < ND) lh[t] = 0u;
    __syncthreads();
    int u = blockIdx.x * 256 + t;
    int d = 0;
#pragma unroll
    for (int j = 0; j < DD; ++j) d += (e[u * DD + j] >= 0) ? 1 : 0;
    deg[u] = d;
    atomicAdd(&lh[d], 1u);
    __syncthreads();
    if (t < ND) atomicAdd(&ghist[t], lh[t]);
}

__global__ void k_scan(const unsigned int* __restrict__ ghist,
                       unsigned int* __restrict__ cursors) {
    unsigned int acc = 0;
    for (int d = 0; d < ND; ++d) { cursors[d] = acc; acc += ghist[d]; }
}

__global__ __launch_bounds__(256) void k_scatter(const int* __restrict__ deg,
                                                 int* __restrict__ order,
                                                 unsigned int* __restrict__ cursors) {
    __shared__ unsigned int lcnt[ND];
    __shared__ unsigned int lbase[ND];
    int t = threadIdx.x;
    if (t < ND) lcnt[t] = 0u;
    __syncthreads();
    int u = blockIdx.x * 256 + t;
    int d = deg[u];
    unsigned int r = atomicAdd(&lcnt[d], 1u);
    __syncthreads();
    if (t < ND) lbase[t] = atomicAdd(&cursors[t], lcnt[t]);
    __syncthreads();
    order[lbase[d] + r] = u;
}

// ---------------- conv: s = self + sum(neigh); y = sigmoid(s @ W[deg] + b[deg]) ----------------

template<int F, int FPAD>
__global__ __launch_bounds__(256) void k_conv(const float* __restrict__ X,
                                              const int* __restrict__ e,
                                              const float* __restrict__ W,
                                              const float* __restrict__ bias,
                                              const int* __restrict__ order,
                                              const int* __restrict__ deg,
                                              float* __restrict__ Y) {
    __shared__ float sT[TILE][F];
    __shared__ float Wc[32][HH];
    __shared__ int vT[TILE];
    __shared__ int eT[TILE * DD];
    __shared__ int degT[TILE];

    const int t = threadIdx.x;
    const int g0 = blockIdx.x * TILE;

    if (t < TILE) {
        int v = order[g0 + t];
        vT[t] = v;
        degT[t] = deg[v];
    }
    __syncthreads();
    for (int i = t; i < TILE * DD; i += 256) {
        eT[i] = e[vT[i / DD] * DD + (i % DD)];
    }
    __syncthreads();

    // phase 1: gather-sum into sT
    {
        constexpr int SH = (FPAD == 64) ? 6 : 7;
        constexpr int NSTEP = 256 / FPAD;
        const int f = t & (FPAD - 1);
        const int nq = t >> SH;
        if (f < F) {
            for (int n = nq; n < TILE; n += NSTEP) {
                int v = vT[n];
                int nbase = v & ~(NN - 1);
                float s = X[(size_t)v * F + f];
#pragma unroll
                for (int j = 0; j < DD; ++j) {
                    int idx = eT[n * DD + j];
                    if (idx >= 0) s += X[(size_t)(nbase + idx) * F + f];
                }
                sT[n][f] = s;
            }
        }
    }
    __syncthreads();

    const int dlo = degT[0];
    const int dhi = degT[TILE - 1];
    const int hq = (t & 31) * 4;     // 4 consecutive h per thread
    const int slot = t >> 5;         // 8 node slots

    for (int d = dlo; d <= dhi; ++d) {
        float4 acc[8];
#pragma unroll
        for (int k = 0; k < 8; ++k) acc[k] = make_float4(0.f, 0.f, 0.f, 0.f);

        for (int f0 = 0; f0 < F; f0 += 32) {
            const int nf = (F - f0 < 32) ? (F - f0) : 32;
            __syncthreads();   // protect Wc from previous chunk's readers
            const float* Wsrc = W + ((size_t)d * F + f0) * HH;
            for (int i = t * 4; i < nf * HH; i += 1024) {
                *(float4*)&Wc[0][i] = *(const float4*)&Wsrc[i];
            }
            __syncthreads();
            for (int f = 0; f < nf; ++f) {
                float4 w = *(const float4*)&Wc[f][hq];
#pragma unroll
                for (int k = 0; k < 8; ++k) {
                    float s = sT[slot + 8 * k][f0 + f];
                    acc[k].x = fmaf(s, w.x, acc[k].x);
                    acc[k].y = fmaf(s, w.y, acc[k].y);
                    acc[k].z = fmaf(s, w.z, acc[k].z);
                    acc[k].w = fmaf(s, w.w, acc[k].w);
                }
            }
        }

        float4 bv = *(const float4*)&bias[d * HH + hq];
#pragma unroll
        for (int k = 0; k < 8; ++k) {
            int n = slot + 8 * k;
            if (degT[n] == d) {
                float4 z;
                z.x = 1.f / (1.f + __expf(-(acc[k].x + bv.x)));
                z.y = 1.f / (1.f + __expf(-(acc[k].y + bv.y)));
                z.z = 1.f / (1.f + __expf(-(acc[k].z + bv.z)));
                z.w = 1.f / (1.f + __expf(-(acc[k].w + bv.w)));
                *(float4*)&Y[(size_t)vT[n] * HH + hq] = z;
            }
        }
    }
}

// ---------------- pool: P[v] = max(X[v], X[neighbors]) ----------------

__global__ __launch_bounds__(256) void k_pool(const float* __restrict__ X,
                                              const int* __restrict__ e,
                                              float* __restrict__ P) {
    const int t = threadIdx.x;
    const int u = blockIdx.x * 8 + (t >> 5);
    const int hq = (t & 31) * 4;
    const int nbase = u & ~(NN - 1);
    float4 m = *(const float4*)&X[(size_t)u * HH + hq];
#pragma unroll
    for (int j = 0; j < DD; ++j) {
        int idx = e[u * DD + j];
        if (idx >= 0) {
            float4 v = *(const float4*)&X[(size_t)(nbase + idx) * HH + hq];
            m.x = fmaxf(m.x, v.x);
            m.y = fmaxf(m.y, v.y);
            m.z = fmaxf(m.z, v.z);
            m.w = fmaxf(m.w, v.w);
        }
    }
    *(float4*)&P[(size_t)u * HH + hq] = m;
}

// ---------------- final: pool + sum over nodes per batch ----------------

__global__ __launch_bounds__(256) void k_pool_sum(const float* __restrict__ X,
                                                  const int* __restrict__ e,
                                                  float* __restrict__ out) {
    __shared__ float red[8][HH];
    const int t = threadIdx.x;
    const int b = blockIdx.x;
    const int slot = t >> 5;
    const int hq = (t & 31) * 4;
    float4 acc = make_float4(0.f, 0.f, 0.f, 0.f);
    for (int n = slot; n < NN; n += 8) {
        int u = b * NN + n;
        float4 m = *(const float4*)&X[(size_t)u * HH + hq];
#pragma unroll
        for (int j = 0; j < DD; ++j) {
            int idx = e[u * DD + j];
            if (idx >= 0) {
                float4 v = *(const float4*)&X[(size_t)(b * NN + idx) * HH + hq];
                m.x = fmaxf(m.x, v.x);
                m.y = fmaxf(m.y, v.y);
                m.z = fmaxf(m.z, v.z);
                m.w = fmaxf(m.w, v.w);
            }
        }
        acc.x += m.x; acc.y += m.y; acc.z += m.z; acc.w += m.w;
    }
    *(float4*)&red[slot][hq] = acc;
    __syncthreads();
    if (t < HH) {
        float s = 0.f;
#pragma unroll
        for (int k = 0; k < 8; ++k) s += red[k][t];
        out[b * HH + t] = s;
    }
}

// ---------------- launcher ----------------

extern "C" void kernel_launch(void* const* d_in, const int* in_sizes, int n_in,
                              void* d_out, int out_size, void* d_ws, size_t ws_size,
                              hipStream_t stream) {
    const float* a  = (const float*)d_in[0];
    const int*   e  = (const int*)d_in[1];
    const float* W0 = (const float*)d_in[2];
    const float* b0 = (const float*)d_in[3];
    const float* W1 = (const float*)d_in[4];
    const float* b1 = (const float*)d_in[5];
    float* out = (float*)d_out;

    char* ws = (char*)d_ws;
    const size_t XBYTES = (size_t)TOTAL * HH * 4;   // 64 MB
    float* xbuf = (float*)ws;
    float* pbuf = (float*)(ws + XBYTES);
    int*   deg  = (int*)(ws + 2 * XBYTES);
    int*   order = (int*)(ws + 2 * XBYTES + (size_t)TOTAL * 4);
    unsigned int* ghist   = (unsigned int*)(ws + 2 * XBYTES + (size_t)TOTAL * 8);
    unsigned int* cursors = ghist + 8;

    hipLaunchKernelGGL(k_zero, dim3(1), dim3(64), 0, stream, ghist);
    hipLaunchKernelGGL(k_hist, dim3(TOTAL / 256), dim3(256), 0, stream, e, deg, ghist);
    hipLaunchKernelGGL(k_scan, dim3(1), dim3(1), 0, stream, ghist, cursors);
    hipLaunchKernelGGL(k_scatter, dim3(TOTAL / 256), dim3(256), 0, stream, deg, order, cursors);

    hipLaunchKernelGGL((k_conv<F_IN, 64>), dim3(TOTAL / TILE), dim3(256), 0, stream,
                       a, e, W0, b0, order, deg, xbuf);
    hipLaunchKernelGGL(k_pool, dim3(TOTAL / 8), dim3(256), 0, stream, xbuf, e, pbuf);
    hipLaunchKernelGGL((k_conv<HH, 128>), dim3(TOTAL / TILE), dim3(256), 0, stream,
                       pbuf, e, W1, b1, order, deg, xbuf);
    hipLaunchKernelGGL(k_pool_sum, dim3(BB), dim3(256), 0, stream, xbuf, e, out);
}

// Round 2
// 227.857 us; speedup vs baseline: 3.8234x; 3.8234x over previous
//
#include <hip/hip_runtime.h>
#include <math.h>

#define BB 256
#define NN 512
#define DD 6
#define F_IN 62
#define HH 128
#define ND 7
#define TOTAL (BB*NN)   // 131072

typedef __bf16 bf16x8 __attribute__((ext_vector_type(8)));
typedef float f32x4 __attribute__((ext_vector_type(4)));

__device__ __forceinline__ unsigned short f2bf(float f) {
    unsigned u = __builtin_bit_cast(unsigned, f);
    u = (u + 0x7FFFu + ((u >> 16) & 1u)) >> 16;
    return (unsigned short)u;
}
__device__ __forceinline__ float lo2f(unsigned x) { return __builtin_bit_cast(float, x << 16); }
__device__ __forceinline__ float hi2f(unsigned x) { return __builtin_bit_cast(float, x & 0xFFFF0000u); }

// ---------------- counting sort of nodes by degree ----------------

__global__ void k_zero(unsigned int* ghist) {
    if (threadIdx.x < ND) ghist[threadIdx.x] = 0u;
}

__global__ __launch_bounds__(256) void k_hist(const int* __restrict__ e,
                                              int* __restrict__ deg,
                                              unsigned int* __restrict__ ghist) {
    __shared__ unsigned int lh[ND];
    int t = threadIdx.x;
    if (t < ND) lh[t] = 0u;
    __syncthreads();
    int u = blockIdx.x * 256 + t;
    int d = 0;
#pragma unroll
    for (int j = 0; j < DD; ++j) d += (e[u * DD + j] >= 0) ? 1 : 0;
    deg[u] = d;
    atomicAdd(&lh[d], 1u);
    __syncthreads();
    if (t < ND) atomicAdd(&ghist[t], lh[t]);
}

__global__ void k_scan(const unsigned int* __restrict__ ghist,
                       unsigned int* __restrict__ cursors) {
    unsigned int acc = 0;
    for (int d = 0; d < ND; ++d) { cursors[d] = acc; acc += ghist[d]; }
}

__global__ __launch_bounds__(256) void k_scatter(const int* __restrict__ deg,
                                                 int* __restrict__ order,
                                                 unsigned int* __restrict__ cursors) {
    __shared__ unsigned int lcnt[ND];
    __shared__ unsigned int lbase[ND];
    int t = threadIdx.x;
    if (t < ND) lcnt[t] = 0u;
    __syncthreads();
    int u = blockIdx.x * 256 + t;
    int d = deg[u];
    unsigned int r = atomicAdd(&lcnt[d], 1u);
    __syncthreads();
    if (t < ND) lbase[t] = atomicAdd(&cursors[t], lcnt[t]);
    __syncthreads();
    order[lbase[d] + r] = u;
}

// ---------------- prep: a (f32 [TOTAL][62]) -> bf16 [TOTAL][64], zero-pad ----------------

__global__ __launch_bounds__(256) void k_prep_a(const float* __restrict__ a,
                                                unsigned short* __restrict__ Ap) {
    int u = blockIdx.x * 256 + threadIdx.x;   // unit = 8 cols
    int r = u >> 3;
    int c0 = (u & 7) * 8;
    unsigned short h[8];
#pragma unroll
    for (int i = 0; i < 8; ++i) {
        int c = c0 + i;
        h[i] = (c < F_IN) ? f2bf(a[(size_t)r * F_IN + c]) : (unsigned short)0;
    }
    uint4 p;
    p.x = (unsigned)h[0] | ((unsigned)h[1] << 16);
    p.y = (unsigned)h[2] | ((unsigned)h[3] << 16);
    p.z = (unsigned)h[4] | ((unsigned)h[5] << 16);
    p.w = (unsigned)h[6] | ((unsigned)h[7] << 16);
    *(uint4*)&Ap[(size_t)r * 64 + c0] = p;
}

// ---------------- prep: W [ND][F][HH] f32 -> WT [ND][HH][K] bf16 (K-contig, pad) ----------------

__global__ void k_prep_wt(const float* __restrict__ W, unsigned short* __restrict__ WT,
                          int F, int K) {
    int n = blockIdx.x;   // 0..127
    int d = blockIdx.y;   // 0..6
    for (int k = threadIdx.x; k < K; k += 64) {
        float v = (k < F) ? W[((size_t)d * F + k) * HH + n] : 0.f;
        WT[((size_t)d * HH + n) * K + k] = f2bf(v);
    }
}

// ---------------- conv via MFMA: Y = sigmoid((self+sum(neigh)) @ W[deg] + b[deg]) ----------------
// Xp: bf16 [TOTAL][K], WT: bf16 [ND][HH][K], Y: bf16 [TOTAL][HH]

template<int KB>   // KB = K/8 (8 for conv1 K=64, 16 for conv2 K=128)
__global__ __launch_bounds__(256, 3)
void k_conv_mfma(const unsigned short* __restrict__ Xp,
                 const int* __restrict__ e,
                 const unsigned short* __restrict__ WT,
                 const float* __restrict__ bias,
                 const int* __restrict__ order,
                 const int* __restrict__ deg,
                 unsigned short* __restrict__ Y) {
    constexpr int K = KB * 8;
    constexpr int LOGKB = (KB == 16) ? 4 : 3;
    __shared__ unsigned short sP[64 * 128];   // gather tile (swizzled) / epilogue staging
    __shared__ int vT[64];
    __shared__ int degT[64];
    __shared__ int eT[64 * DD];

    const int t = threadIdx.x;
    const int l = t & 63;
    const int w = t >> 6;

    if (t < 64) {
        int v = order[blockIdx.x * 64 + t];
        vT[t] = v;
        degT[t] = deg[v];
    }
    __syncthreads();
    for (int i = t; i < 64 * DD; i += 256) eT[i] = e[vT[i / DD] * DD + (i % DD)];
    __syncthreads();

    // phase 1: gather-sum (f32) -> bf16 -> swizzled LDS [n][kb ^ (n&7)] units of 8
    for (int u = t; u < 64 * KB; u += 256) {
        const int kb = u & (KB - 1);
        const int n = u >> LOGKB;
        const int v = vT[n];
        const int nbase = v & ~(NN - 1);
        float s[8];
        {
            uint4 p = *(const uint4*)(Xp + (size_t)v * K + kb * 8);
            s[0] = lo2f(p.x); s[1] = hi2f(p.x); s[2] = lo2f(p.y); s[3] = hi2f(p.y);
            s[4] = lo2f(p.z); s[5] = hi2f(p.z); s[6] = lo2f(p.w); s[7] = hi2f(p.w);
        }
#pragma unroll
        for (int j = 0; j < DD; ++j) {
            int idx = eT[n * DD + j];
            if (idx >= 0) {
                uint4 p = *(const uint4*)(Xp + (size_t)(nbase + idx) * K + kb * 8);
                s[0] += lo2f(p.x); s[1] += hi2f(p.x); s[2] += lo2f(p.y); s[3] += hi2f(p.y);
                s[4] += lo2f(p.z); s[5] += hi2f(p.z); s[6] += lo2f(p.w); s[7] += hi2f(p.w);
            }
        }
        uint4 r;
        r.x = (unsigned)f2bf(s[0]) | ((unsigned)f2bf(s[1]) << 16);
        r.y = (unsigned)f2bf(s[2]) | ((unsigned)f2bf(s[3]) << 16);
        r.z = (unsigned)f2bf(s[4]) | ((unsigned)f2bf(s[5]) << 16);
        r.w = (unsigned)f2bf(s[6]) | ((unsigned)f2bf(s[7]) << 16);
        const int kbs = kb ^ (n & 7);
        *(uint4*)&sP[(n * KB + kbs) * 8] = r;
    }
    __syncthreads();

    const int dlo = degT[0];
    const int dhi = degT[63];
    const int lr = l & 15;
    const int lq = l >> 4;

    for (int d = dlo; d <= dhi; ++d) {
        // B fragments: wave w owns output cols [32w, 32w+32); k contiguous per lane
        bf16x8 bf[K / 32][2];
#pragma unroll
        for (int kk = 0; kk < K / 32; ++kk)
#pragma unroll
            for (int nb = 0; nb < 2; ++nb) {
                int ncol = w * 32 + nb * 16 + lr;
                int krow = kk * 32 + lq * 8;
                bf[kk][nb] = *(const bf16x8*)(WT + ((size_t)d * HH + ncol) * K + krow);
            }

        f32x4 acc[4][2];
#pragma unroll
        for (int mb = 0; mb < 4; ++mb)
#pragma unroll
            for (int nb = 0; nb < 2; ++nb) {
                f32x4 z = {0.f, 0.f, 0.f, 0.f};
                acc[mb][nb] = z;
            }

#pragma unroll
        for (int kk = 0; kk < K / 32; ++kk) {
#pragma unroll
            for (int mb = 0; mb < 4; ++mb) {
                int nrow = mb * 16 + lr;
                int kbp = kk * 4 + lq;
                int kbs = kbp ^ (nrow & 7);
                bf16x8 af = *(const bf16x8*)&sP[(nrow * KB + kbs) * 8];
                acc[mb][0] = __builtin_amdgcn_mfma_f32_16x16x32_bf16(af, bf[kk][0], acc[mb][0], 0, 0, 0);
                acc[mb][1] = __builtin_amdgcn_mfma_f32_16x16x32_bf16(af, bf[kk][1], acc[mb][1], 0, 0, 0);
            }
        }

        if (dlo == dhi) {
            __syncthreads();   // all A-frag reads done; reuse sP as [64][HH] staging
#pragma unroll
            for (int mb = 0; mb < 4; ++mb)
#pragma unroll
                for (int nb = 0; nb < 2; ++nb) {
                    int col = w * 32 + nb * 16 + lr;
                    float bv = bias[d * HH + col];
#pragma unroll
                    for (int r = 0; r < 4; ++r) {
                        int n = mb * 16 + lq * 4 + r;
                        float z = 1.f / (1.f + __expf(-(acc[mb][nb][r] + bv)));
                        sP[n * HH + col] = f2bf(z);
                    }
                }
            __syncthreads();
            for (int u = t; u < 64 * HH / 8; u += 256) {
                int n = u >> 4;
                int c8 = (u & 15) * 8;
                uint4 p = *(const uint4*)&sP[n * HH + c8];
                *(uint4*)&Y[(size_t)vT[n] * HH + c8] = p;
            }
        } else {
            // rare degree-boundary block: masked scalar stores
#pragma unroll
            for (int mb = 0; mb < 4; ++mb)
#pragma unroll
                for (int nb = 0; nb < 2; ++nb) {
                    int col = w * 32 + nb * 16 + lr;
                    float bv = bias[d * HH + col];
#pragma unroll
                    for (int r = 0; r < 4; ++r) {
                        int n = mb * 16 + lq * 4 + r;
                        if (degT[n] == d) {
                            float z = 1.f / (1.f + __expf(-(acc[mb][nb][r] + bv)));
                            Y[(size_t)vT[n] * HH + col] = f2bf(z);
                        }
                    }
                }
        }
    }
}

// ---------------- pool: P[v] = max(X[v], X[neighbors]) on bf16 rows ----------------

__global__ __launch_bounds__(256) void k_pool_bf(const unsigned short* __restrict__ X,
                                                 const int* __restrict__ e,
                                                 unsigned short* __restrict__ P) {
    const int t = threadIdx.x;
    const int u = blockIdx.x * 16 + (t >> 4);
    const int c8 = (t & 15) * 8;
    const int nbase = u & ~(NN - 1);
    float m[8];
    {
        uint4 p = *(const uint4*)(X + (size_t)u * HH + c8);
        m[0] = lo2f(p.x); m[1] = hi2f(p.x); m[2] = lo2f(p.y); m[3] = hi2f(p.y);
        m[4] = lo2f(p.z); m[5] = hi2f(p.z); m[6] = lo2f(p.w); m[7] = hi2f(p.w);
    }
#pragma unroll
    for (int j = 0; j < DD; ++j) {
        int idx = e[u * DD + j];
        if (idx >= 0) {
            uint4 p = *(const uint4*)(X + (size_t)(nbase + idx) * HH + c8);
            m[0] = fmaxf(m[0], lo2f(p.x)); m[1] = fmaxf(m[1], hi2f(p.x));
            m[2] = fmaxf(m[2], lo2f(p.y)); m[3] = fmaxf(m[3], hi2f(p.y));
            m[4] = fmaxf(m[4], lo2f(p.z)); m[5] = fmaxf(m[5], hi2f(p.z));
            m[6] = fmaxf(m[6], lo2f(p.w)); m[7] = fmaxf(m[7], hi2f(p.w));
        }
    }
    uint4 r;
    r.x = (unsigned)f2bf(m[0]) | ((unsigned)f2bf(m[1]) << 16);
    r.y = (unsigned)f2bf(m[2]) | ((unsigned)f2bf(m[3]) << 16);
    r.z = (unsigned)f2bf(m[4]) | ((unsigned)f2bf(m[5]) << 16);
    r.w = (unsigned)f2bf(m[6]) | ((unsigned)f2bf(m[7]) << 16);
    *(uint4*)&P[(size_t)u * HH + c8] = r;
}

// ---------------- final: pool + sum over nodes per batch (f32 out) ----------------

__global__ __launch_bounds__(256) void k_pool_sum_bf(const unsigned short* __restrict__ X,
                                                     const int* __restrict__ e,
                                                     float* __restrict__ out) {
    __shared__ float red[16][HH];
    const int t = threadIdx.x;
    const int b = blockIdx.x;
    const int slot = t >> 4;
    const int c8 = (t & 15) * 8;
    float acc[8];
#pragma unroll
    for (int i = 0; i < 8; ++i) acc[i] = 0.f;

    for (int n = slot; n < NN; n += 16) {
        int u = b * NN + n;
        float m[8];
        uint4 p = *(const uint4*)(X + (size_t)u * HH + c8);
        m[0] = lo2f(p.x); m[1] = hi2f(p.x); m[2] = lo2f(p.y); m[3] = hi2f(p.y);
        m[4] = lo2f(p.z); m[5] = hi2f(p.z); m[6] = lo2f(p.w); m[7] = hi2f(p.w);
#pragma unroll
        for (int j = 0; j < DD; ++j) {
            int idx = e[u * DD + j];
            if (idx >= 0) {
                uint4 q = *(const uint4*)(X + (size_t)(b * NN + idx) * HH + c8);
                m[0] = fmaxf(m[0], lo2f(q.x)); m[1] = fmaxf(m[1], hi2f(q.x));
                m[2] = fmaxf(m[2], lo2f(q.y)); m[3] = fmaxf(m[3], hi2f(q.y));
                m[4] = fmaxf(m[4], lo2f(q.z)); m[5] = fmaxf(m[5], hi2f(q.z));
                m[6] = fmaxf(m[6], lo2f(q.w)); m[7] = fmaxf(m[7], hi2f(q.w));
            }
        }
#pragma unroll
        for (int i = 0; i < 8; ++i) acc[i] += m[i];
    }
#pragma unroll
    for (int i = 0; i < 8; ++i) red[slot][c8 + i] = acc[i];
    __syncthreads();
    if (t < HH) {
        float s = 0.f;
#pragma unroll
        for (int k = 0; k < 16; ++k) s += red[k][t];
        out[b * HH + t] = s;
    }
}

// ---------------- launcher ----------------

extern "C" void kernel_launch(void* const* d_in, const int* in_sizes, int n_in,
                              void* d_out, int out_size, void* d_ws, size_t ws_size,
                              hipStream_t stream) {
    const float* a  = (const float*)d_in[0];
    const int*   e  = (const int*)d_in[1];
    const float* W0 = (const float*)d_in[2];
    const float* b0 = (const float*)d_in[3];
    const float* W1 = (const float*)d_in[4];
    const float* b1 = (const float*)d_in[5];
    float* out = (float*)d_out;

    char* ws = (char*)d_ws;
    const size_t XB = (size_t)TOTAL * HH * 2;    // 32 MB bf16
    unsigned short* xbuf = (unsigned short*)ws;
    unsigned short* pbuf = (unsigned short*)(ws + XB);
    unsigned short* Ap   = (unsigned short*)(ws + 2 * XB);                 // 16 MB
    unsigned short* WT0  = (unsigned short*)(ws + 2 * XB + (size_t)TOTAL * 64 * 2);
    unsigned short* WT1  = WT0 + (size_t)ND * HH * 64;
    char* ip = (char*)(WT1 + (size_t)ND * HH * 128);
    int* deg   = (int*)ip;
    int* order = (int*)(ip + (size_t)TOTAL * 4);
    unsigned int* ghist   = (unsigned int*)(ip + (size_t)TOTAL * 8);
    unsigned int* cursors = ghist + 8;

    hipLaunchKernelGGL(k_zero, dim3(1), dim3(64), 0, stream, ghist);
    hipLaunchKernelGGL(k_hist, dim3(TOTAL / 256), dim3(256), 0, stream, e, deg, ghist);
    hipLaunchKernelGGL(k_scan, dim3(1), dim3(1), 0, stream, ghist, cursors);
    hipLaunchKernelGGL(k_scatter, dim3(TOTAL / 256), dim3(256), 0, stream, deg, order, cursors);

    hipLaunchKernelGGL(k_prep_a, dim3(TOTAL * 8 / 256), dim3(256), 0, stream, a, Ap);
    hipLaunchKernelGGL(k_prep_wt, dim3(HH, ND), dim3(64), 0, stream, W0, WT0, F_IN, 64);
    hipLaunchKernelGGL(k_prep_wt, dim3(HH, ND), dim3(64), 0, stream, W1, WT1, HH, 128);

    hipLaunchKernelGGL((k_conv_mfma<8>),  dim3(TOTAL / 64), dim3(256), 0, stream,
                       Ap, e, WT0, b0, order, deg, xbuf);
    hipLaunchKernelGGL(k_pool_bf, dim3(TOTAL / 16), dim3(256), 0, stream, xbuf, e, pbuf);
    hipLaunchKernelGGL((k_conv_mfma<16>), dim3(TOTAL / 64), dim3(256), 0, stream,
                       pbuf, e, WT1, b1, order, deg, xbuf);
    hipLaunchKernelGGL(k_pool_sum_bf, dim3(BB), dim3(256), 0, stream, xbuf, e, out);
}

// Round 3
// 170.480 us; speedup vs baseline: 5.1102x; 1.3366x over previous
//
#include <hip/hip_runtime.h>
#include <math.h>

#define BB 256
#define NN 512
#define DD 6
#define F_IN 62
#define HH 128
#define ND 7
#define TOTAL (BB*NN)   // 131072

typedef __bf16 bf16x8 __attribute__((ext_vector_type(8)));
typedef float f32x4 __attribute__((ext_vector_type(4)));

__device__ __forceinline__ unsigned short f2bf(float f) {
    unsigned u = __builtin_bit_cast(unsigned, f);
    u = (u + 0x7FFFu + ((u >> 16) & 1u)) >> 16;
    return (unsigned short)u;
}
__device__ __forceinline__ float lo2f(unsigned x) { return __builtin_bit_cast(float, x << 16); }
__device__ __forceinline__ float hi2f(unsigned x) { return __builtin_bit_cast(float, x & 0xFFFF0000u); }

// ---------------- counting sort of nodes by degree ----------------

__global__ void k_zero(unsigned int* ghist) {
    if (threadIdx.x < ND) ghist[threadIdx.x] = 0u;
}

__global__ __launch_bounds__(256) void k_hist(const int* __restrict__ e,
                                              int* __restrict__ deg,
                                              unsigned int* __restrict__ ghist) {
    __shared__ unsigned int lh[ND];
    int t = threadIdx.x;
    if (t < ND) lh[t] = 0u;
    __syncthreads();
    int u = blockIdx.x * 256 + t;
    int d = 0;
#pragma unroll
    for (int j = 0; j < DD; ++j) d += (e[u * DD + j] >= 0) ? 1 : 0;
    deg[u] = d;
    atomicAdd(&lh[d], 1u);
    __syncthreads();
    if (t < ND) atomicAdd(&ghist[t], lh[t]);
}

__global__ void k_scan(const unsigned int* __restrict__ ghist,
                       unsigned int* __restrict__ cursors) {
    unsigned int acc = 0;
    for (int d = 0; d < ND; ++d) { cursors[d] = acc; acc += ghist[d]; }
}

__global__ __launch_bounds__(256) void k_scatter(const int* __restrict__ deg,
                                                 int* __restrict__ order,
                                                 unsigned int* __restrict__ cursors) {
    __shared__ unsigned int lcnt[ND];
    __shared__ unsigned int lbase[ND];
    int t = threadIdx.x;
    if (t < ND) lcnt[t] = 0u;
    __syncthreads();
    int u = blockIdx.x * 256 + t;
    int d = deg[u];
    unsigned int r = atomicAdd(&lcnt[d], 1u);
    __syncthreads();
    if (t < ND) lbase[t] = atomicAdd(&cursors[t], lcnt[t]);
    __syncthreads();
    order[lbase[d] + r] = u;
}

// ---------------- prep: a (f32 [TOTAL][62]) -> bf16 [TOTAL][64], zero-pad ----------------

__global__ __launch_bounds__(256) void k_prep_a(const float* __restrict__ a,
                                                unsigned short* __restrict__ Ap) {
    int u = blockIdx.x * 256 + threadIdx.x;   // unit = 8 cols
    int r = u >> 3;
    int c0 = (u & 7) * 8;
    unsigned short h[8];
#pragma unroll
    for (int i = 0; i < 8; ++i) {
        int c = c0 + i;
        h[i] = (c < F_IN) ? f2bf(a[(size_t)r * F_IN + c]) : (unsigned short)0;
    }
    uint4 p;
    p.x = (unsigned)h[0] | ((unsigned)h[1] << 16);
    p.y = (unsigned)h[2] | ((unsigned)h[3] << 16);
    p.z = (unsigned)h[4] | ((unsigned)h[5] << 16);
    p.w = (unsigned)h[6] | ((unsigned)h[7] << 16);
    *(uint4*)&Ap[(size_t)r * 64 + c0] = p;
}

// ---------------- prep: W [ND][F][HH] f32 -> WT [ND][HH][K] bf16 (K-contig, pad) ----------------

__global__ void k_prep_wt(const float* __restrict__ W, unsigned short* __restrict__ WT,
                          int F, int K) {
    int n = blockIdx.x;   // 0..127
    int d = blockIdx.y;   // 0..6
    for (int k = threadIdx.x; k < K; k += 64) {
        float v = (k < F) ? W[((size_t)d * F + k) * HH + n] : 0.f;
        WT[((size_t)d * HH + n) * K + k] = f2bf(v);
    }
}

// ---------------- conv via MFMA: Y = sigmoid((self+sum(neigh)) @ W[deg] + b[deg]) ----------------
// Xp: bf16 [TOTAL][K], WT: bf16 [ND][HH][K], Y: bf16 [TOTAL][HH]

template<int KB>   // KB = K/8 (8 for conv1 K=64, 16 for conv2 K=128)
__global__ __launch_bounds__(256, 3)
void k_conv_mfma(const unsigned short* __restrict__ Xp,
                 const int* __restrict__ e,
                 const unsigned short* __restrict__ WT,
                 const float* __restrict__ bias,
                 const int* __restrict__ order,
                 const int* __restrict__ deg,
                 unsigned short* __restrict__ Y) {
    constexpr int K = KB * 8;
    constexpr int LOGKB = (KB == 16) ? 4 : 3;
    __shared__ unsigned short sP[64 * 128];   // gather tile (swizzled) / epilogue staging
    __shared__ int vT[64];
    __shared__ int degT[64];
    __shared__ int eT[64 * DD];

    const int t = threadIdx.x;
    const int l = t & 63;
    const int w = t >> 6;

    if (t < 64) {
        int v = order[blockIdx.x * 64 + t];
        vT[t] = v;
        degT[t] = deg[v];
    }
    __syncthreads();
    for (int i = t; i < 64 * DD; i += 256) eT[i] = e[vT[i / DD] * DD + (i % DD)];
    __syncthreads();

    // phase 1: gather-sum (f32) -> bf16 -> swizzled LDS [n][kb ^ (n&7)] units of 8
    for (int u = t; u < 64 * KB; u += 256) {
        const int kb = u & (KB - 1);
        const int n = u >> LOGKB;
        const int v = vT[n];
        const int nbase = v & ~(NN - 1);
        float s[8];
        {
            uint4 p = *(const uint4*)(Xp + (size_t)v * K + kb * 8);
            s[0] = lo2f(p.x); s[1] = hi2f(p.x); s[2] = lo2f(p.y); s[3] = hi2f(p.y);
            s[4] = lo2f(p.z); s[5] = hi2f(p.z); s[6] = lo2f(p.w); s[7] = hi2f(p.w);
        }
#pragma unroll
        for (int j = 0; j < DD; ++j) {
            int idx = eT[n * DD + j];
            if (idx >= 0) {
                uint4 p = *(const uint4*)(Xp + (size_t)(nbase + idx) * K + kb * 8);
                s[0] += lo2f(p.x); s[1] += hi2f(p.x); s[2] += lo2f(p.y); s[3] += hi2f(p.y);
                s[4] += lo2f(p.z); s[5] += hi2f(p.z); s[6] += lo2f(p.w); s[7] += hi2f(p.w);
            }
        }
        uint4 r;
        r.x = (unsigned)f2bf(s[0]) | ((unsigned)f2bf(s[1]) << 16);
        r.y = (unsigned)f2bf(s[2]) | ((unsigned)f2bf(s[3]) << 16);
        r.z = (unsigned)f2bf(s[4]) | ((unsigned)f2bf(s[5]) << 16);
        r.w = (unsigned)f2bf(s[6]) | ((unsigned)f2bf(s[7]) << 16);
        const int kbs = kb ^ (n & 7);
        *(uint4*)&sP[(n * KB + kbs) * 8] = r;
    }
    __syncthreads();

    const int dlo = degT[0];
    const int dhi = degT[63];
    const int lr = l & 15;
    const int lq = l >> 4;

    for (int d = dlo; d <= dhi; ++d) {
        // B fragments: wave w owns output cols [32w, 32w+32); k contiguous per lane
        bf16x8 bf[K / 32][2];
#pragma unroll
        for (int kk = 0; kk < K / 32; ++kk)
#pragma unroll
            for (int nb = 0; nb < 2; ++nb) {
                int ncol = w * 32 + nb * 16 + lr;
                int krow = kk * 32 + lq * 8;
                bf[kk][nb] = *(const bf16x8*)(WT + ((size_t)d * HH + ncol) * K + krow);
            }

        f32x4 acc[4][2];
#pragma unroll
        for (int mb = 0; mb < 4; ++mb)
#pragma unroll
            for (int nb = 0; nb < 2; ++nb) {
                f32x4 z = {0.f, 0.f, 0.f, 0.f};
                acc[mb][nb] = z;
            }

#pragma unroll
        for (int kk = 0; kk < K / 32; ++kk) {
#pragma unroll
            for (int mb = 0; mb < 4; ++mb) {
                int nrow = mb * 16 + lr;
                int kbp = kk * 4 + lq;
                int kbs = kbp ^ (nrow & 7);
                bf16x8 af = *(const bf16x8*)&sP[(nrow * KB + kbs) * 8];
                acc[mb][0] = __builtin_amdgcn_mfma_f32_16x16x32_bf16(af, bf[kk][0], acc[mb][0], 0, 0, 0);
                acc[mb][1] = __builtin_amdgcn_mfma_f32_16x16x32_bf16(af, bf[kk][1], acc[mb][1], 0, 0, 0);
            }
        }

        if (dlo == dhi) {
            __syncthreads();   // all A-frag reads done; reuse sP as [64][HH] staging
#pragma unroll
            for (int mb = 0; mb < 4; ++mb)
#pragma unroll
                for (int nb = 0; nb < 2; ++nb) {
                    int col = w * 32 + nb * 16 + lr;
                    float bv = bias[d * HH + col];
#pragma unroll
                    for (int r = 0; r < 4; ++r) {
                        int n = mb * 16 + lq * 4 + r;
                        float z = 1.f / (1.f + __expf(-(acc[mb][nb][r] + bv)));
                        sP[n * HH + col] = f2bf(z);
                    }
                }
            __syncthreads();
            for (int u = t; u < 64 * HH / 8; u += 256) {
                int n = u >> 4;
                int c8 = (u & 15) * 8;
                uint4 p = *(const uint4*)&sP[n * HH + c8];
                *(uint4*)&Y[(size_t)vT[n] * HH + c8] = p;
            }
        } else {
            // rare degree-boundary block: masked scalar stores
#pragma unroll
            for (int mb = 0; mb < 4; ++mb)
#pragma unroll
                for (int nb = 0; nb < 2; ++nb) {
                    int col = w * 32 + nb * 16 + lr;
                    float bv = bias[d * HH + col];
#pragma unroll
                    for (int r = 0; r < 4; ++r) {
                        int n = mb * 16 + lq * 4 + r;
                        if (degT[n] == d) {
                            float z = 1.f / (1.f + __expf(-(acc[mb][nb][r] + bv)));
                            Y[(size_t)vT[n] * HH + col] = f2bf(z);
                        }
                    }
                }
        }
    }
}

// ---------------- pool: P[v] = max(X[v], X[neighbors]) on bf16 rows ----------------

__global__ __launch_bounds__(256) void k_pool_bf(const unsigned short* __restrict__ X,
                                                 const int* __restrict__ e,
                                                 unsigned short* __restrict__ P) {
    const int t = threadIdx.x;
    const int u = blockIdx.x * 16 + (t >> 4);
    const int c8 = (t & 15) * 8;
    const int nbase = u & ~(NN - 1);
    float m[8];
    {
        uint4 p = *(const uint4*)(X + (size_t)u * HH + c8);
        m[0] = lo2f(p.x); m[1] = hi2f(p.x); m[2] = lo2f(p.y); m[3] = hi2f(p.y);
        m[4] = lo2f(p.z); m[5] = hi2f(p.z); m[6] = lo2f(p.w); m[7] = hi2f(p.w);
    }
#pragma unroll
    for (int j = 0; j < DD; ++j) {
        int idx = e[u * DD + j];
        if (idx >= 0) {
            uint4 p = *(const uint4*)(X + (size_t)(nbase + idx) * HH + c8);
            m[0] = fmaxf(m[0], lo2f(p.x)); m[1] = fmaxf(m[1], hi2f(p.x));
            m[2] = fmaxf(m[2], lo2f(p.y)); m[3] = fmaxf(m[3], hi2f(p.y));
            m[4] = fmaxf(m[4], lo2f(p.z)); m[5] = fmaxf(m[5], hi2f(p.z));
            m[6] = fmaxf(m[6], lo2f(p.w)); m[7] = fmaxf(m[7], hi2f(p.w));
        }
    }
    uint4 r;
    r.x = (unsigned)f2bf(m[0]) | ((unsigned)f2bf(m[1]) << 16);
    r.y = (unsigned)f2bf(m[2]) | ((unsigned)f2bf(m[3]) << 16);
    r.z = (unsigned)f2bf(m[4]) | ((unsigned)f2bf(m[5]) << 16);
    r.w = (unsigned)f2bf(m[6]) | ((unsigned)f2bf(m[7]) << 16);
    *(uint4*)&P[(size_t)u * HH + c8] = r;
}

// ---------------- final: pool + partial sum (8 blocks per batch) ----------------

__global__ __launch_bounds__(256) void k_pool_sum_part(const unsigned short* __restrict__ X,
                                                       const int* __restrict__ e,
                                                       float* __restrict__ partial) {
    __shared__ float red[16][HH + 4];
    const int t = threadIdx.x;
    const int b = blockIdx.x >> 3;
    const int chunk = blockIdx.x & 7;
    const int slot = t >> 4;
    const int c8 = (t & 15) * 8;
    float acc[8];
#pragma unroll
    for (int i = 0; i < 8; ++i) acc[i] = 0.f;

    for (int n = chunk * 64 + slot; n < chunk * 64 + 64; n += 16) {
        int u = b * NN + n;
        float m[8];
        uint4 p = *(const uint4*)(X + (size_t)u * HH + c8);
        m[0] = lo2f(p.x); m[1] = hi2f(p.x); m[2] = lo2f(p.y); m[3] = hi2f(p.y);
        m[4] = lo2f(p.z); m[5] = hi2f(p.z); m[6] = lo2f(p.w); m[7] = hi2f(p.w);
#pragma unroll
        for (int j = 0; j < DD; ++j) {
            int idx = e[u * DD + j];
            if (idx >= 0) {
                uint4 q = *(const uint4*)(X + (size_t)(b * NN + idx) * HH + c8);
                m[0] = fmaxf(m[0], lo2f(q.x)); m[1] = fmaxf(m[1], hi2f(q.x));
                m[2] = fmaxf(m[2], lo2f(q.y)); m[3] = fmaxf(m[3], hi2f(q.y));
                m[4] = fmaxf(m[4], lo2f(q.z)); m[5] = fmaxf(m[5], hi2f(q.z));
                m[6] = fmaxf(m[6], lo2f(q.w)); m[7] = fmaxf(m[7], hi2f(q.w));
            }
        }
#pragma unroll
        for (int i = 0; i < 8; ++i) acc[i] += m[i];
    }
#pragma unroll
    for (int i = 0; i < 8; ++i) red[slot][c8 + i] = acc[i];
    __syncthreads();
    if (t < HH) {
        float s = 0.f;
#pragma unroll
        for (int k = 0; k < 16; ++k) s += red[k][t];
        partial[(size_t)blockIdx.x * HH + t] = s;
    }
}

// ---------------- final reduce: out[b][c] = sum of 8 partials (deterministic) ----------------

__global__ __launch_bounds__(256) void k_sum_final(const float* __restrict__ partial,
                                                   float* __restrict__ out) {
    int g = blockIdx.x * 256 + threadIdx.x;   // b*HH + c, 32768 total
    int b = g >> 7;
    int c = g & 127;
    float s = 0.f;
#pragma unroll
    for (int k = 0; k < 8; ++k) s += partial[(size_t)(b * 8 + k) * HH + c];
    out[g] = s;
}

// ---------------- launcher ----------------

extern "C" void kernel_launch(void* const* d_in, const int* in_sizes, int n_in,
                              void* d_out, int out_size, void* d_ws, size_t ws_size,
                              hipStream_t stream) {
    const float* a  = (const float*)d_in[0];
    const int*   e  = (const int*)d_in[1];
    const float* W0 = (const float*)d_in[2];
    const float* b0 = (const float*)d_in[3];
    const float* W1 = (const float*)d_in[4];
    const float* b1 = (const float*)d_in[5];
    float* out = (float*)d_out;

    char* ws = (char*)d_ws;
    const size_t XB = (size_t)TOTAL * HH * 2;    // 32 MB bf16
    unsigned short* xbuf = (unsigned short*)ws;
    unsigned short* pbuf = (unsigned short*)(ws + XB);
    unsigned short* Ap   = (unsigned short*)(ws + 2 * XB);                 // 16 MB
    float* partial = (float*)Ap;   // reuse: Ap dead after conv1; partial used at the end (1 MB)
    unsigned short* WT0  = (unsigned short*)(ws + 2 * XB + (size_t)TOTAL * 64 * 2);
    unsigned short* WT1  = WT0 + (size_t)ND * HH * 64;
    char* ip = (char*)(WT1 + (size_t)ND * HH * 128);
    int* deg   = (int*)ip;
    int* order = (int*)(ip + (size_t)TOTAL * 4);
    unsigned int* ghist   = (unsigned int*)(ip + (size_t)TOTAL * 8);
    unsigned int* cursors = ghist + 8;

    hipLaunchKernelGGL(k_zero, dim3(1), dim3(64), 0, stream, ghist);
    hipLaunchKernelGGL(k_hist, dim3(TOTAL / 256), dim3(256), 0, stream, e, deg, ghist);
    hipLaunchKernelGGL(k_scan, dim3(1), dim3(1), 0, stream, ghist, cursors);
    hipLaunchKernelGGL(k_scatter, dim3(TOTAL / 256), dim3(256), 0, stream, deg, order, cursors);

    hipLaunchKernelGGL(k_prep_a, dim3(TOTAL * 8 / 256), dim3(256), 0, stream, a, Ap);
    hipLaunchKernelGGL(k_prep_wt, dim3(HH, ND), dim3(64), 0, stream, W0, WT0, F_IN, 64);
    hipLaunchKernelGGL(k_prep_wt, dim3(HH, ND), dim3(64), 0, stream, W1, WT1, HH, 128);

    hipLaunchKernelGGL((k_conv_mfma<8>),  dim3(TOTAL / 64), dim3(256), 0, stream,
                       Ap, e, WT0, b0, order, deg, xbuf);
    hipLaunchKernelGGL(k_pool_bf, dim3(TOTAL / 16), dim3(256), 0, stream, xbuf, e, pbuf);
    hipLaunchKernelGGL((k_conv_mfma<16>), dim3(TOTAL / 64), dim3(256), 0, stream,
                       pbuf, e, WT1, b1, order, deg, xbuf);
    hipLaunchKernelGGL(k_pool_sum_part, dim3(BB * 8), dim3(256), 0, stream, xbuf, e, partial);
    hipLaunchKernelGGL(k_sum_final, dim3(BB * HH / 256), dim3(256), 0, stream, partial, out);
}

// Round 4
// 163.439 us; speedup vs baseline: 5.3304x; 1.0431x over previous
//
#include <hip/hip_runtime.h>
#include <math.h>

#define BB 256
#define NN 512
#define DD 6
#define F_IN 62
#define HH 128
#define ND 7
#define TOTAL (BB*NN)   // 131072

typedef __bf16 bf16x8 __attribute__((ext_vector_type(8)));
typedef float f32x4 __attribute__((ext_vector_type(4)));

__device__ __forceinline__ unsigned short f2bf(float f) {
    unsigned u = __builtin_bit_cast(unsigned, f);
    u = (u + 0x7FFFu + ((u >> 16) & 1u)) >> 16;
    return (unsigned short)u;
}
__device__ __forceinline__ float lo2f(unsigned x) { return __builtin_bit_cast(float, x << 16); }
__device__ __forceinline__ float hi2f(unsigned x) { return __builtin_bit_cast(float, x & 0xFFFF0000u); }

// ---------------- per-batch counting sort by degree (one block per batch) ----------------
// Tiles of 64 within a batch are degree-homogeneous-ish AND batch-local -> L2-resident gathers.

__global__ __launch_bounds__(512) void k_sort_batch(const int* __restrict__ e,
                                                    int* __restrict__ deg,
                                                    int* __restrict__ order) {
    __shared__ unsigned int lh[ND];
    __shared__ unsigned int base[ND];
    const int b = blockIdx.x;
    const int t = threadIdx.x;
    if (t < ND) lh[t] = 0u;
    __syncthreads();
    const int u = b * NN + t;
    int d = 0;
#pragma unroll
    for (int j = 0; j < DD; ++j) d += (e[u * DD + j] >= 0) ? 1 : 0;
    deg[u] = d;
    unsigned int r = atomicAdd(&lh[d], 1u);
    __syncthreads();
    if (t == 0) {
        unsigned int acc = 0;
        for (int k = 0; k < ND; ++k) { base[k] = acc; acc += lh[k]; }
    }
    __syncthreads();
    order[b * NN + base[d] + r] = u;
}

// ---------------- prep: a (f32 [TOTAL][62]) -> bf16 [TOTAL][64], zero-pad ----------------

__global__ __launch_bounds__(256) void k_prep_a(const float* __restrict__ a,
                                                unsigned short* __restrict__ Ap) {
    int u = blockIdx.x * 256 + threadIdx.x;   // unit = 8 cols
    int r = u >> 3;
    int c0 = (u & 7) * 8;
    unsigned short h[8];
#pragma unroll
    for (int i = 0; i < 8; ++i) {
        int c = c0 + i;
        h[i] = (c < F_IN) ? f2bf(a[(size_t)r * F_IN + c]) : (unsigned short)0;
    }
    uint4 p;
    p.x = (unsigned)h[0] | ((unsigned)h[1] << 16);
    p.y = (unsigned)h[2] | ((unsigned)h[3] << 16);
    p.z = (unsigned)h[4] | ((unsigned)h[5] << 16);
    p.w = (unsigned)h[6] | ((unsigned)h[7] << 16);
    *(uint4*)&Ap[(size_t)r * 64 + c0] = p;
}

// ---------------- prep: W [ND][F][HH] f32 -> WT [ND][HH][K] bf16 (K-contig, pad) ----------------

__global__ void k_prep_wt(const float* __restrict__ W, unsigned short* __restrict__ WT,
                          int F, int K) {
    int n = blockIdx.x;   // 0..127
    int d = blockIdx.y;   // 0..6
    for (int k = threadIdx.x; k < K; k += 64) {
        float v = (k < F) ? W[((size_t)d * F + k) * HH + n] : 0.f;
        WT[((size_t)d * HH + n) * K + k] = f2bf(v);
    }
}

// ---------------- conv via MFMA: Y = sigmoid((self+sum(neigh)) @ W[deg] + b[deg]) ----------------
// Xp: bf16 [TOTAL][K], WT: bf16 [ND][HH][K], Y: bf16 [TOTAL][HH]
// Grid = 2048 = 8 tiles x 256 batches, XCD-swizzled: all 8 tiles of a batch on one XCD.

template<int KB>   // KB = K/8 (8 for conv1 K=64, 16 for conv2 K=128)
__global__ __launch_bounds__(256, 3)
void k_conv_mfma(const unsigned short* __restrict__ Xp,
                 const int* __restrict__ e,
                 const unsigned short* __restrict__ WT,
                 const float* __restrict__ bias,
                 const int* __restrict__ order,
                 const int* __restrict__ deg,
                 unsigned short* __restrict__ Y) {
    constexpr int K = KB * 8;
    constexpr int LOGKB = (KB == 16) ? 4 : 3;
    __shared__ unsigned short sP[64 * 128];   // gather tile (swizzled) / epilogue staging
    __shared__ int vT[64];
    __shared__ int degT[64];
    __shared__ int eT[64 * DD];

    const int t = threadIdx.x;
    const int l = t & 63;
    const int w = t >> 6;

    // XCD-aware mapping: xcd = bi&7 fixed by dispatch round-robin; group batches per XCD.
    const int bi = blockIdx.x;
    const int x8 = bi & 7;
    const int j = bi >> 3;
    const int batch = x8 + 8 * (j >> 3);
    const int tile = j & 7;
    const int g0 = batch * NN + tile * 64;

    if (t < 64) {
        int v = order[g0 + t];
        vT[t] = v;
        degT[t] = deg[v];
    }
    __syncthreads();
    for (int i = t; i < 64 * DD; i += 256) eT[i] = e[vT[i / DD] * DD + (i % DD)];
    __syncthreads();

    // phase 1: gather-sum (f32) -> bf16 -> swizzled LDS [n][kb ^ (n&7)] units of 8
    for (int u = t; u < 64 * KB; u += 256) {
        const int kb = u & (KB - 1);
        const int n = u >> LOGKB;
        const int v = vT[n];
        const int nbase = v & ~(NN - 1);
        float s[8];
        {
            uint4 p = *(const uint4*)(Xp + (size_t)v * K + kb * 8);
            s[0] = lo2f(p.x); s[1] = hi2f(p.x); s[2] = lo2f(p.y); s[3] = hi2f(p.y);
            s[4] = lo2f(p.z); s[5] = hi2f(p.z); s[6] = lo2f(p.w); s[7] = hi2f(p.w);
        }
#pragma unroll
        for (int jj = 0; jj < DD; ++jj) {
            int idx = eT[n * DD + jj];
            if (idx >= 0) {
                uint4 p = *(const uint4*)(Xp + (size_t)(nbase + idx) * K + kb * 8);
                s[0] += lo2f(p.x); s[1] += hi2f(p.x); s[2] += lo2f(p.y); s[3] += hi2f(p.y);
                s[4] += lo2f(p.z); s[5] += hi2f(p.z); s[6] += lo2f(p.w); s[7] += hi2f(p.w);
            }
        }
        uint4 r;
        r.x = (unsigned)f2bf(s[0]) | ((unsigned)f2bf(s[1]) << 16);
        r.y = (unsigned)f2bf(s[2]) | ((unsigned)f2bf(s[3]) << 16);
        r.z = (unsigned)f2bf(s[4]) | ((unsigned)f2bf(s[5]) << 16);
        r.w = (unsigned)f2bf(s[6]) | ((unsigned)f2bf(s[7]) << 16);
        const int kbs = kb ^ (n & 7);
        *(uint4*)&sP[(n * KB + kbs) * 8] = r;
    }
    __syncthreads();

    const int dlo = degT[0];
    const int dhi = degT[63];
    const int lr = l & 15;
    const int lq = l >> 4;

    for (int d = dlo; d <= dhi; ++d) {
        // B fragments: wave w owns output cols [32w, 32w+32); k contiguous per lane
        bf16x8 bf[K / 32][2];
#pragma unroll
        for (int kk = 0; kk < K / 32; ++kk)
#pragma unroll
            for (int nb = 0; nb < 2; ++nb) {
                int ncol = w * 32 + nb * 16 + lr;
                int krow = kk * 32 + lq * 8;
                bf[kk][nb] = *(const bf16x8*)(WT + ((size_t)d * HH + ncol) * K + krow);
            }

        f32x4 acc[4][2];
#pragma unroll
        for (int mb = 0; mb < 4; ++mb)
#pragma unroll
            for (int nb = 0; nb < 2; ++nb) {
                f32x4 z = {0.f, 0.f, 0.f, 0.f};
                acc[mb][nb] = z;
            }

#pragma unroll
        for (int kk = 0; kk < K / 32; ++kk) {
#pragma unroll
            for (int mb = 0; mb < 4; ++mb) {
                int nrow = mb * 16 + lr;
                int kbp = kk * 4 + lq;
                int kbs = kbp ^ (nrow & 7);
                bf16x8 af = *(const bf16x8*)&sP[(nrow * KB + kbs) * 8];
                acc[mb][0] = __builtin_amdgcn_mfma_f32_16x16x32_bf16(af, bf[kk][0], acc[mb][0], 0, 0, 0);
                acc[mb][1] = __builtin_amdgcn_mfma_f32_16x16x32_bf16(af, bf[kk][1], acc[mb][1], 0, 0, 0);
            }
        }

        if (dlo == dhi) {
            __syncthreads();   // all A-frag reads done; reuse sP as [64][HH] staging
#pragma unroll
            for (int mb = 0; mb < 4; ++mb)
#pragma unroll
                for (int nb = 0; nb < 2; ++nb) {
                    int col = w * 32 + nb * 16 + lr;
                    float bv = bias[d * HH + col];
#pragma unroll
                    for (int r = 0; r < 4; ++r) {
                        int n = mb * 16 + lq * 4 + r;
                        float z = 1.f / (1.f + __expf(-(acc[mb][nb][r] + bv)));
                        sP[n * HH + col] = f2bf(z);
                    }
                }
            __syncthreads();
            for (int u = t; u < 64 * HH / 8; u += 256) {
                int n = u >> 4;
                int c8 = (u & 15) * 8;
                uint4 p = *(const uint4*)&sP[n * HH + c8];
                *(uint4*)&Y[(size_t)vT[n] * HH + c8] = p;
            }
        } else {
            // degree-boundary block: masked scalar stores
#pragma unroll
            for (int mb = 0; mb < 4; ++mb)
#pragma unroll
                for (int nb = 0; nb < 2; ++nb) {
                    int col = w * 32 + nb * 16 + lr;
                    float bv = bias[d * HH + col];
#pragma unroll
                    for (int r = 0; r < 4; ++r) {
                        int n = mb * 16 + lq * 4 + r;
                        if (degT[n] == d) {
                            float z = 1.f / (1.f + __expf(-(acc[mb][nb][r] + bv)));
                            Y[(size_t)vT[n] * HH + col] = f2bf(z);
                        }
                    }
                }
        }
    }
}

// ---------------- pool: P[v] = max(X[v], X[neighbors]) on bf16 rows ----------------
// Grid = 8192 = 32 blocks x 256 batches, XCD-swizzled.

__global__ __launch_bounds__(256) void k_pool_bf(const unsigned short* __restrict__ X,
                                                 const int* __restrict__ e,
                                                 unsigned short* __restrict__ P) {
    const int t = threadIdx.x;
    const int bi = blockIdx.x;
    const int x8 = bi & 7;
    const int j = bi >> 3;
    const int batch = x8 + 8 * (j >> 5);
    const int sub = j & 31;
    const int u = batch * NN + sub * 16 + (t >> 4);
    const int c8 = (t & 15) * 8;
    const int nbase = u & ~(NN - 1);
    float m[8];
    {
        uint4 p = *(const uint4*)(X + (size_t)u * HH + c8);
        m[0] = lo2f(p.x); m[1] = hi2f(p.x); m[2] = lo2f(p.y); m[3] = hi2f(p.y);
        m[4] = lo2f(p.z); m[5] = hi2f(p.z); m[6] = lo2f(p.w); m[7] = hi2f(p.w);
    }
#pragma unroll
    for (int jj = 0; jj < DD; ++jj) {
        int idx = e[u * DD + jj];
        if (idx >= 0) {
            uint4 p = *(const uint4*)(X + (size_t)(nbase + idx) * HH + c8);
            m[0] = fmaxf(m[0], lo2f(p.x)); m[1] = fmaxf(m[1], hi2f(p.x));
            m[2] = fmaxf(m[2], lo2f(p.y)); m[3] = fmaxf(m[3], hi2f(p.y));
            m[4] = fmaxf(m[4], lo2f(p.z)); m[5] = fmaxf(m[5], hi2f(p.z));
            m[6] = fmaxf(m[6], lo2f(p.w)); m[7] = fmaxf(m[7], hi2f(p.w));
        }
    }
    uint4 r;
    r.x = (unsigned)f2bf(m[0]) | ((unsigned)f2bf(m[1]) << 16);
    r.y = (unsigned)f2bf(m[2]) | ((unsigned)f2bf(m[3]) << 16);
    r.z = (unsigned)f2bf(m[4]) | ((unsigned)f2bf(m[5]) << 16);
    r.w = (unsigned)f2bf(m[6]) | ((unsigned)f2bf(m[7]) << 16);
    *(uint4*)&P[(size_t)u * HH + c8] = r;
}

// ---------------- final: pool + partial sum (8 blocks per batch, XCD-swizzled) ----------------

__global__ __launch_bounds__(256) void k_pool_sum_part(const unsigned short* __restrict__ X,
                                                       const int* __restrict__ e,
                                                       float* __restrict__ partial) {
    __shared__ float red[16][HH + 4];
    const int t = threadIdx.x;
    const int bi = blockIdx.x;
    const int x8 = bi & 7;
    const int j = bi >> 3;
    const int b = x8 + 8 * (j >> 3);
    const int chunk = j & 7;
    const int slot = t >> 4;
    const int c8 = (t & 15) * 8;
    float acc[8];
#pragma unroll
    for (int i = 0; i < 8; ++i) acc[i] = 0.f;

    for (int n = chunk * 64 + slot; n < chunk * 64 + 64; n += 16) {
        int u = b * NN + n;
        float m[8];
        uint4 p = *(const uint4*)(X + (size_t)u * HH + c8);
        m[0] = lo2f(p.x); m[1] = hi2f(p.x); m[2] = lo2f(p.y); m[3] = hi2f(p.y);
        m[4] = lo2f(p.z); m[5] = hi2f(p.z); m[6] = lo2f(p.w); m[7] = hi2f(p.w);
#pragma unroll
        for (int jj = 0; jj < DD; ++jj) {
            int idx = e[u * DD + jj];
            if (idx >= 0) {
                uint4 q = *(const uint4*)(X + (size_t)(b * NN + idx) * HH + c8);
                m[0] = fmaxf(m[0], lo2f(q.x)); m[1] = fmaxf(m[1], hi2f(q.x));
                m[2] = fmaxf(m[2], lo2f(q.y)); m[3] = fmaxf(m[3], hi2f(q.y));
                m[4] = fmaxf(m[4], lo2f(q.z)); m[5] = fmaxf(m[5], hi2f(q.z));
                m[6] = fmaxf(m[6], lo2f(q.w)); m[7] = fmaxf(m[7], hi2f(q.w));
            }
        }
#pragma unroll
        for (int i = 0; i < 8; ++i) acc[i] += m[i];
    }
#pragma unroll
    for (int i = 0; i < 8; ++i) red[slot][c8 + i] = acc[i];
    __syncthreads();
    if (t < HH) {
        float s = 0.f;
#pragma unroll
        for (int k = 0; k < 16; ++k) s += red[k][t];
        partial[(size_t)(b * 8 + chunk) * HH + t] = s;
    }
}

// ---------------- final reduce: out[b][c] = sum of 8 partials (deterministic) ----------------

__global__ __launch_bounds__(256) void k_sum_final(const float* __restrict__ partial,
                                                   float* __restrict__ out) {
    int g = blockIdx.x * 256 + threadIdx.x;   // b*HH + c, 32768 total
    int b = g >> 7;
    int c = g & 127;
    float s = 0.f;
#pragma unroll
    for (int k = 0; k < 8; ++k) s += partial[(size_t)(b * 8 + k) * HH + c];
    out[g] = s;
}

// ---------------- launcher ----------------

extern "C" void kernel_launch(void* const* d_in, const int* in_sizes, int n_in,
                              void* d_out, int out_size, void* d_ws, size_t ws_size,
                              hipStream_t stream) {
    const float* a  = (const float*)d_in[0];
    const int*   e  = (const int*)d_in[1];
    const float* W0 = (const float*)d_in[2];
    const float* b0 = (const float*)d_in[3];
    const float* W1 = (const float*)d_in[4];
    const float* b1 = (const float*)d_in[5];
    float* out = (float*)d_out;

    char* ws = (char*)d_ws;
    const size_t XB = (size_t)TOTAL * HH * 2;    // 32 MB bf16
    unsigned short* xbuf = (unsigned short*)ws;
    unsigned short* pbuf = (unsigned short*)(ws + XB);
    unsigned short* Ap   = (unsigned short*)(ws + 2 * XB);                 // 16 MB
    float* partial = (float*)Ap;   // reuse: Ap dead after conv1; partial used at the end (1 MB)
    unsigned short* WT0  = (unsigned short*)(ws + 2 * XB + (size_t)TOTAL * 64 * 2);
    unsigned short* WT1  = WT0 + (size_t)ND * HH * 64;
    char* ip = (char*)(WT1 + (size_t)ND * HH * 128);
    int* deg   = (int*)ip;
    int* order = (int*)(ip + (size_t)TOTAL * 4);

    hipLaunchKernelGGL(k_sort_batch, dim3(BB), dim3(NN), 0, stream, e, deg, order);

    hipLaunchKernelGGL(k_prep_a, dim3(TOTAL * 8 / 256), dim3(256), 0, stream, a, Ap);
    hipLaunchKernelGGL(k_prep_wt, dim3(HH, ND), dim3(64), 0, stream, W0, WT0, F_IN, 64);
    hipLaunchKernelGGL(k_prep_wt, dim3(HH, ND), dim3(64), 0, stream, W1, WT1, HH, 128);

    hipLaunchKernelGGL((k_conv_mfma<8>),  dim3(TOTAL / 64), dim3(256), 0, stream,
                       Ap, e, WT0, b0, order, deg, xbuf);
    hipLaunchKernelGGL(k_pool_bf, dim3(TOTAL / 16), dim3(256), 0, stream, xbuf, e, pbuf);
    hipLaunchKernelGGL((k_conv_mfma<16>), dim3(TOTAL / 64), dim3(256), 0, stream,
                       pbuf, e, WT1, b1, order, deg, xbuf);
    hipLaunchKernelGGL(k_pool_sum_part, dim3(BB * 8), dim3(256), 0, stream, xbuf, e, partial);
    hipLaunchKernelGGL(k_sum_final, dim3(BB * HH / 256), dim3(256), 0, stream, partial, out);
}